// Round 3
// baseline (273.882 us; speedup 1.0000x reference)
//
#include <hip/hip_runtime.h>

// x: (8, 320, 128, 128) fp32.  C=320 ≡ 0 mod 5  =>  plane%5 == channel%5.
// out(i,j) = (silu(x[s1]) + x[i,j]) * (sigmoid(silu(x[s2])) - 0.5)
// t=c%5: 0: s1=(i,j+1), s2=(i,j+2)   (mod 128)
//        1: s1=(i,j-1), s2=(i,j-2)
//        2: s1=(i+1,j), s2=(i+2,j)
//        3: s1=(i-1,j), s2=(i-2,j)
//        4: s1=s2=(i,j)
//
// Producer-side form: s(p)=silu(x(p)), g(p)=sigmoid(s(p))-0.5 computed once
// per element; out(p) = (s(shift1(p)) + x(p)) * g(shift2(p)). Neighbor s,g
// move bit-exactly via shuffle (W shifts) or an LDS tile (H shifts).
//
// Round-3 changes (halo latency/locality, t=2,3 path):
//  - XCD-aware block swizzle (no NT stores this time): the 8 blocks of a
//    plane run consecutively on ONE XCD, so the 2 halo rows (owned by the
//    neighboring block) are local-L2 hits instead of cross-XCD HBM misses.
//  - Halo global load issued right after x0 (before the own s,g trans
//    chain) so its latency is overlapped, not exposed at __syncthreads.

#define PLANE_ELEMS 16384   // 128*128

__device__ __forceinline__ float fsig(float z) {
    // 1/(1+exp(-z)) native exp + native rcp; verified absmax 0.015625 (passes).
    return __builtin_amdgcn_rcpf(1.0f + __expf(-z));
}

__global__ __launch_bounds__(512) void ablock_kernel(const float* __restrict__ x,
                                                     float* __restrict__ out,
                                                     int nv4) {
    // 18 rows of s,g per block: 16 owned + 2 halo. 36.9 KB -> 4 blocks/CU.
    __shared__ float4 s_lds[18][32];
    __shared__ float4 g_lds[18][32];

    // XCD swizzle: bijective since gridDim (20480) % 8 == 0. Consecutive
    // hardware-dispatch slots (orig bid, round-robin over 8 XCDs) map to
    // contiguous logical chunks per XCD -> a plane's 8 blocks share an XCD L2.
    int bid = blockIdx.x;
    {
        int nb = gridDim.x;
        if ((nb & 7) == 0) {
            int cpx = nb >> 3;
            bid = (bid & 7) * cpx + (bid >> 3);
        }
    }

    const int tid   = threadIdx.x;
    const int g     = bid * 512 + tid;  // float4 index (grid exact)
    const int lane  = tid & 63;
    const int plane = g >> 12;        // 4096 float4 per plane
    const int o     = g & 4095;
    const int li    = tid >> 5;       // local row 0..15 (block = 16 rows)
    const int c4    = tid & 31;       // float4 col within row
    const int row   = o >> 5;         // plane row
    const int t     = plane % 5;      // block-uniform (block = 1/8 plane)

    const float4* p4 = (const float4*)(x + (size_t)plane * PLANE_ELEMS);
    const float4  x0 = p4[o];         // issued first (vmcnt-oldest)

    // Issue the halo load NOW, before the trans chain, so its latency hides
    // under the own s,g computation instead of stalling the barrier.
    const bool hpath = (t == 2) || (t == 3);
    float4 xh;
    int hidx = 0;
    if (hpath && tid < 64) {
        int k    = tid >> 5;          // 0,1
        int hc4  = tid & 31;
        int row0 = row - li;          // block's first plane row
        int hrow;
        if (t == 2) { hidx = 16 + k; hrow = (row0 + 16 + k) & 127; }
        else        { hidx = k;      hrow = (row0 - 2 + k) & 127; }
        xh = p4[(hrow << 5) + hc4];
    }

    // Own s,g (all paths need exactly these).
    float4 s, gg;
    s.x = x0.x * fsig(x0.x);  s.y = x0.y * fsig(x0.y);
    s.z = x0.z * fsig(x0.z);  s.w = x0.w * fsig(x0.w);
    gg.x = fsig(s.x) - 0.5f;  gg.y = fsig(s.y) - 0.5f;
    gg.z = fsig(s.z) - 0.5f;  gg.w = fsig(s.w) - 0.5f;

    float4 r;

    if (t == 0) {
        // out_j = (s_{j+1} + x_j) * g_{j+2}; need next thread's s.x, g.x, g.y.
        // Row = 32 float4 = one half-wave; ring within half-wave.
        int src = (lane & 32) | ((lane + 1) & 31);
        float snx = __shfl(s.x,  src, 64);
        float gnx = __shfl(gg.x, src, 64);
        float gny = __shfl(gg.y, src, 64);
        r.x = (s.y + x0.x) * gg.z;
        r.y = (s.z + x0.y) * gg.w;
        r.z = (s.w + x0.z) * gnx;
        r.w = (snx + x0.w) * gny;
    } else if (t == 1) {
        // out_j = (s_{j-1} + x_j) * g_{j-2}; need prev thread's s.w, g.z, g.w.
        int src = (lane & 32) | ((lane - 1) & 31);
        float spw = __shfl(s.w,  src, 64);
        float gpz = __shfl(gg.z, src, 64);
        float gpw = __shfl(gg.w, src, 64);
        r.x = (spw + x0.x) * gpz;
        r.y = (s.x + x0.y) * gpw;
        r.z = (s.y + x0.z) * gg.x;
        r.w = (s.z + x0.w) * gg.y;
    } else if (t == 4) {
        r.x = (s.x + x0.x) * gg.x;
        r.y = (s.y + x0.y) * gg.y;
        r.z = (s.z + x0.z) * gg.z;
        r.w = (s.w + x0.w) * gg.w;
    } else {
        // t==2: out(i) = (s(i+1)+x(i))*g(i+2); LDS idx m <-> plane row row0+m.
        // t==3: out(i) = (s(i-1)+x(i))*g(i-2); LDS idx m <-> plane row row0+m-2.
        const int base = (t == 2) ? li : li + 2;
        s_lds[base][c4] = s;
        g_lds[base][c4] = gg;

        if (tid < 64) {               // halo s,g from the pre-issued load
            int hc4 = tid & 31;
            float4 hs, hg;
            hs.x = xh.x * fsig(xh.x);  hs.y = xh.y * fsig(xh.y);
            hs.z = xh.z * fsig(xh.z);  hs.w = xh.w * fsig(xh.w);
            hg.x = fsig(hs.x) - 0.5f;  hg.y = fsig(hs.y) - 0.5f;
            hg.z = fsig(hs.z) - 0.5f;  hg.w = fsig(hs.w) - 0.5f;
            s_lds[hidx][hc4] = hs;
            g_lds[hidx][hc4] = hg;
        }
        __syncthreads();   // block-uniform branch (t uniform per block)

        float4 s1 = s_lds[li + 1][c4];   // shift-1 row (both t=2 and t=3)
        float4 g2;
        if (t == 2) g2 = g_lds[li + 2][c4];
        else        g2 = g_lds[li][c4];
        r.x = (s1.x + x0.x) * g2.x;
        r.y = (s1.y + x0.y) * g2.y;
        r.z = (s1.z + x0.z) * g2.z;
        r.w = (s1.w + x0.w) * g2.w;
    }

    ((float4*)out)[g] = r;
}

extern "C" void kernel_launch(void* const* d_in, const int* in_sizes, int n_in,
                              void* d_out, int out_size, void* d_ws, size_t ws_size,
                              hipStream_t stream) {
    const float* x   = (const float*)d_in[0];
    float*       out = (float*)d_out;
    int n   = in_sizes[0];        // 41,943,040
    int nv4 = n >> 2;             // 10,485,760 float4
    int block = 512;              // 16 rows per block (LDS tile for H shifts)
    int grid  = nv4 / block;      // 20,480 (exact, divisible by 8)
    ablock_kernel<<<grid, block, 0, stream>>>(x, out, nv4);
}